// Round 5
// baseline (102.549 us; speedup 1.0000x reference)
//
#include <hip/hip_runtime.h>

// SNN excitatory layer only (inhibitory layer never affects the returned
// spikes — the scan discards its carry).
//
// R4 changes vs R3:
//  - TLP: each neuron row is split across TWO waves (1024 cols each) ->
//    4096 waves = 4 waves/SIMD (was 2), 4 blocks/CU. Waves on a SIMD come
//    from different blocks -> staggered stalls actually overlap.
//  - Half-partials exchanged via a tiny double-buffered LDS slot, one
//    __syncthreads per step. R3 insight still holds: partial(t) is only
//    consumed by step t+1's syn update -> exchange latency is off the
//    critical path.
//  - Spike-branch t_pre loads issue right after `spike` is known (step top),
//    ~150 cy ahead of first use.

constexpr int T_STEPS = 128;
constexpr int N_IN    = 2048;
constexpr int N_EXC   = 2048;
constexpr int HALF    = N_IN / 2;          // 1024 columns per wave

// t_pre[t][j]: trace AFTER the step-t update (what stdp_step's dw uses).
__global__ __launch_bounds__(256)
void tp_precompute_kernel(const float* __restrict__ x, float* __restrict__ tp_ws) {
    const int j = blockIdx.x * blockDim.x + threadIdx.x;
    float tp = 0.f;
    #pragma unroll 4
    for (int t = 0; t < T_STEPS; ++t) {
        tp = fmaf(0.05f, x[t * N_IN + j] - tp, tp);
        tp_ws[t * N_IN + j] = tp;
    }
}

template <int CTRL, int RM>
__device__ __forceinline__ float dpp_add(float x) {
    int t = __builtin_amdgcn_update_dpp(0, __builtin_bit_cast(int, x),
                                        CTRL, RM, 0xF, true);
    return x + __builtin_bit_cast(float, t);
}

// After this chain, lane 63 holds the 64-lane sum.
__device__ __forceinline__ float wave_sum64_to_lane63(float x) {
    x = dpp_add<0x111, 0xF>(x);   // row_shr:1
    x = dpp_add<0x112, 0xF>(x);   // row_shr:2
    x = dpp_add<0x114, 0xF>(x);   // row_shr:4
    x = dpp_add<0x118, 0xF>(x);   // row_shr:8
    x = dpp_add<0x142, 0xA>(x);   // row_bcast:15 -> rows 1,3
    x = dpp_add<0x143, 0xC>(x);   // row_bcast:31 -> rows 2,3
    return x;
}

__global__ __launch_bounds__(256, 4)
void snn_exc_kernel(const float* __restrict__ x,     // [T, N_IN]
                    const float* __restrict__ w0,    // [N_EXC, N_IN]
                    const float* __restrict__ tp_ws, // [T, N_IN]
                    float* __restrict__ out)         // [T, N_EXC]
{
    __shared__ float part[2][2][2];    // [buf][neuron-in-block][half]

    const int tid  = threadIdx.x;
    const int lane = tid & 63;
    const int wid  = tid >> 6;
    const int ni   = wid >> 1;          // neuron within block (0..1)
    const int half = wid & 1;           // which 1024-column half
    const int row  = blockIdx.x * 2 + ni;

    // lane l owns columns j = half*1024 + m*256 + l*4 + {0..3}, m = 0..3
    float w[16];
    {
        const float4* wrow = reinterpret_cast<const float4*>(
            w0 + (size_t)row * N_IN + half * HALF);
        #pragma unroll
        for (int m = 0; m < 4; ++m) {
            float4 t4 = wrow[m * 64 + lane];
            w[4*m+0] = t4.x; w[4*m+1] = t4.y; w[4*m+2] = t4.z; w[4*m+3] = t4.w;
        }
    }

    const float4* xbase = reinterpret_cast<const float4*>(x) + half * (HALF / 4) + lane;
    const float4* tpb   = reinterpret_cast<const float4*>(tp_ws) + half * (HALF / 4) + lane;

    float4 xa[4], xb[4];
    #pragma unroll
    for (int m = 0; m < 4; ++m) xa[m] = xbase[m * 64];   // x_0 (own half)

    if (tid < 8) reinterpret_cast<float*>(part)[tid] = 0.f;
    __syncthreads();

    float v = 0.f, syn = 0.f, rho = 0.f, tpost = 0.f;

    // Invariant at entry of step t: syn == i(t-2); LDS buf[(t+1)&1] holds the
    // two half-partials of inp(t-1).  (t=0: both are zero.)
    auto step = [&](int t, const float4 (&xc)[4], float4 (&xn)[4]) {
        // ---- (1) prefetch x_{t+1} (own half) ----
        const int tn = (t + 1 < T_STEPS) ? (t + 1) : (T_STEPS - 1);
        const float4* xv = xbase + (size_t)tn * (N_IN / 4);
        #pragma unroll
        for (int m = 0; m < 4; ++m) xn[m] = xv[m * 64];

        // ---- (2) complete i(t-1) from the step-(t-1) half-partials ----
        const float p0 = part[(t + 1) & 1][ni][0];
        const float p1 = part[(t + 1) & 1][ni][1];
        syn = fmaf(0.8f, syn, p0 + p1);             // i(t-1)

        // ---- (3) scalar LIF (identical in both half-waves) ----
        const float v_dec = fmaf(0.1f, syn - v, v);
        const bool refrac = (rho > 0.f);
        const bool spike  = (v_dec > 1.0f) && !refrac;
        v   = (spike || refrac) ? 0.f : v_dec;
        rho = spike ? 5.0f : fmaxf(rho - (refrac ? 1.f : 0.f), 0.f);
        const float zf = spike ? 1.f : 0.f;
        tpost = fmaf(0.05f, zf - tpost, tpost);
        const float c2 = 1e-3f * tpost;
        if (half == 0 && lane == 0) out[t * N_EXC + row] = zf;

        // ---- (4) issue t_pre loads EARLY on spike steps (used in (6)) ----
        float4 tq[4];
        if (spike) {
            const float4* tq4 = tpb + (size_t)t * (N_IN / 4);
            #pragma unroll
            for (int m = 0; m < 4; ++m) tq[m] = tq4[m * 64];
        }

        // ---- (5) dot product over PRE-update w (own half) ----
        float a0 = 0.f, a1 = 0.f, a2 = 0.f, a3 = 0.f;
        #pragma unroll
        for (int m = 0; m < 4; ++m) {
            a0 = fmaf(xc[m].x, w[4*m+0], a0);
            a1 = fmaf(xc[m].y, w[4*m+1], a1);
            a2 = fmaf(xc[m].z, w[4*m+2], a2);
            a3 = fmaf(xc[m].w, w[4*m+3], a3);
        }

        // ---- (6) STDP weight update (wave-uniform branch) ----
        if (spike) {
            #pragma unroll
            for (int m = 0; m < 4; ++m) {
                w[4*m+0] = fmaxf(fmaf(1e-3f, tq[m].x, fmaf(-c2, xc[m].x, w[4*m+0])), 0.f);
                w[4*m+1] = fmaxf(fmaf(1e-3f, tq[m].y, fmaf(-c2, xc[m].y, w[4*m+1])), 0.f);
                w[4*m+2] = fmaxf(fmaf(1e-3f, tq[m].z, fmaf(-c2, xc[m].z, w[4*m+2])), 0.f);
                w[4*m+3] = fmaxf(fmaf(1e-3f, tq[m].w, fmaf(-c2, xc[m].w, w[4*m+3])), 0.f);
            }
        } else {
            #pragma unroll
            for (int m = 0; m < 4; ++m) {
                w[4*m+0] = fmaxf(fmaf(-c2, xc[m].x, w[4*m+0]), 0.f);
                w[4*m+1] = fmaxf(fmaf(-c2, xc[m].y, w[4*m+1]), 0.f);
                w[4*m+2] = fmaxf(fmaf(-c2, xc[m].z, w[4*m+2]), 0.f);
                w[4*m+3] = fmaxf(fmaf(-c2, xc[m].w, w[4*m+3]), 0.f);
            }
        }

        // ---- (7) reduce own half, publish partial for step t+1 ----
        const float s = wave_sum64_to_lane63((a0 + a1) + (a2 + a3));
        if (lane == 63) part[t & 1][ni][half] = s;
        __syncthreads();
    };

    for (int t = 0; t < T_STEPS; t += 2) {
        step(t,     xa, xb);
        step(t + 1, xb, xa);
    }
}

extern "C" void kernel_launch(void* const* d_in, const int* in_sizes, int n_in,
                              void* d_out, int out_size, void* d_ws, size_t ws_size,
                              hipStream_t stream) {
    const float* x  = (const float*)d_in[0];   // exc_currents [128, 2048] f32
    const float* w0 = (const float*)d_in[1];   // w_exc [2048, 2048] f32
    // d_in[2] (w_inh) unused: inhibitory layer does not affect the output
    float* out = (float*)d_out;                // spikes [128, 2048] f32

    float* tp_ws = (float*)d_ws;               // 1 MiB, ws_size is ample
    tp_precompute_kernel<<<N_IN / 256, 256, 0, stream>>>(x, tp_ws);

    dim3 grid(N_EXC / 2);                      // 1024 blocks, 2 neurons each
    dim3 block(256);                           // 4 waves = 2 neurons x 2 halves
    snn_exc_kernel<<<grid, block, 0, stream>>>(x, w0, tp_ws, out);
}

// Round 6
// 90.927 us; speedup vs baseline: 1.1278x; 1.1278x over previous
//
#include <hip/hip_runtime.h>

// SNN excitatory layer only (inhibitory layer never affects the returned
// spikes — the scan discards its carry).
//
// R5 changes vs R3 (R4's wave-split regressed -> reverted to R3 structure):
//  - model: duration ~ total instruction count; so CUT instructions.
//  - STDP update = ONE v_fma with the VOP3 clamp bit: med3(fma,0,1) is
//    folded by LLVM's tryFoldClamp into fma+clamp. Also restores the exact
//    reference [0,1] clip. (Worst case: v_med3 == old v_max count.)
//  - rho update simplified to spike ? 5 : max(rho-1,0) (exact: rho is
//    integer-valued, refrac=1 iff rho>0).
//  - running pointers for x-prefetch / out store; loop peeled so the
//    prefetch needs no per-step min(t+1,127) select.
//  - spike-path t_pre loads issue at step top (spike known before the dot:
//    v_dec uses the OLD synaptic current).

constexpr int T_STEPS = 128;
constexpr int N_IN    = 2048;
constexpr int N_EXC   = 2048;

// t_pre[t][j]: trace AFTER the step-t update (what stdp_step's dw uses).
__global__ __launch_bounds__(256)
void tp_precompute_kernel(const float* __restrict__ x, float* __restrict__ tp_ws) {
    const int j = blockIdx.x * blockDim.x + threadIdx.x;
    float tp = 0.f;
    #pragma unroll 4
    for (int t = 0; t < T_STEPS; ++t) {
        tp = fmaf(0.05f, x[t * N_IN + j] - tp, tp);
        tp_ws[t * N_IN + j] = tp;
    }
}

template <int CTRL, int RM>
__device__ __forceinline__ float dpp_add(float x) {
    int t = __builtin_amdgcn_update_dpp(0, __builtin_bit_cast(int, x),
                                        CTRL, RM, 0xF, true);
    return x + __builtin_bit_cast(float, t);
}

// Sum across 64 lanes; returns wave-uniform scalar (readlane 63 -> SGPR).
__device__ __forceinline__ float wave_sum64(float x) {
    x = dpp_add<0x111, 0xF>(x);   // row_shr:1
    x = dpp_add<0x112, 0xF>(x);   // row_shr:2
    x = dpp_add<0x114, 0xF>(x);   // row_shr:4
    x = dpp_add<0x118, 0xF>(x);   // row_shr:8
    x = dpp_add<0x142, 0xA>(x);   // row_bcast:15 -> rows 1,3
    x = dpp_add<0x143, 0xC>(x);   // row_bcast:31 -> rows 2,3
    return __builtin_bit_cast(float,
        __builtin_amdgcn_readlane(__builtin_bit_cast(int, x), 63));
}

__device__ __forceinline__ float clamp01(float x) {
    return __builtin_amdgcn_fmed3f(x, 0.f, 1.f);   // folds to clamp bit
}

__global__ __launch_bounds__(256, 2)
void snn_exc_kernel(const float* __restrict__ x,     // [T, N_IN]
                    const float* __restrict__ w0,    // [N_EXC, N_IN]
                    const float* __restrict__ tp_ws, // [T, N_IN]
                    float* __restrict__ out)         // [T, N_EXC]
{
    const int lane = threadIdx.x & 63;
    const int wid  = threadIdx.x >> 6;
    const int row  = blockIdx.x * 4 + wid;

    // lane l owns columns j = m*256 + l*4 + {0..3}, m = 0..7
    float w[32];
    {
        const float4* wrow = reinterpret_cast<const float4*>(w0 + (size_t)row * N_IN);
        #pragma unroll
        for (int m = 0; m < 8; ++m) {
            float4 t4 = wrow[m * 64 + lane];
            w[4*m+0] = t4.x; w[4*m+1] = t4.y; w[4*m+2] = t4.z; w[4*m+3] = t4.w;
        }
    }

    const float4* xbase = reinterpret_cast<const float4*>(x) + lane;
    const float4* tpb   = reinterpret_cast<const float4*>(tp_ws) + lane;
    float*        outp  = out + row;

    float4 xa[8], xb[8];
    #pragma unroll
    for (int m = 0; m < 8; ++m) xa[m] = xbase[m * 64];   // x_0

    const float4* xpf = xbase + (N_IN / 4);              // points at row t+1

    float v = 0.f, syn = 0.f, rho = 0.f, tpost = 0.f;

    auto step = [&](int t, bool pf, const float4 (&xc)[8], float4 (&xn)[8]) {
        // ---- (1) prefetch x_{t+1} via running pointer ----
        if (pf) {
            #pragma unroll
            for (int m = 0; m < 8; ++m) xn[m] = xpf[m * 64];
        }
        xpf += N_IN / 4;

        // ---- (2) scalar LIF: spike known BEFORE the dot (v_dec uses the
        //          OLD synaptic current) ----
        const float v_dec = fmaf(0.1f, syn - v, v);
        const bool refrac = (rho > 0.f);
        const bool spike  = (v_dec > 1.0f) && !refrac;
        v   = (spike || refrac) ? 0.f : v_dec;
        rho = spike ? 5.0f : fmaxf(rho - 1.0f, 0.f);
        const float zf = spike ? 1.f : 0.f;
        tpost = fmaf(0.05f, zf - tpost, tpost);
        const float c2 = 1e-3f * tpost;
        if (lane == 0) *outp = zf;
        outp += N_EXC;

        // ---- (3) early t_pre loads on spike steps (~16% of steps) ----
        float4 tq[8];
        if (spike) {
            const float4* tq4 = tpb + (size_t)t * (N_IN / 4);
            #pragma unroll
            for (int m = 0; m < 8; ++m) tq[m] = tq4[m * 64];
        }

        // ---- (4) dot product over PRE-update w ----
        float a0 = 0.f, a1 = 0.f, a2 = 0.f, a3 = 0.f;
        #pragma unroll
        for (int m = 0; m < 8; ++m) {
            a0 = fmaf(xc[m].x, w[4*m+0], a0);
            a1 = fmaf(xc[m].y, w[4*m+1], a1);
            a2 = fmaf(xc[m].z, w[4*m+2], a2);
            a3 = fmaf(xc[m].w, w[4*m+3], a3);
        }

        // ---- (5) STDP update: 1 fma(+clamp) per element non-spike,
        //          2 fma (outer clamped) on spike steps ----
        if (spike) {
            #pragma unroll
            for (int m = 0; m < 8; ++m) {
                w[4*m+0] = clamp01(fmaf(1e-3f, tq[m].x, fmaf(-c2, xc[m].x, w[4*m+0])));
                w[4*m+1] = clamp01(fmaf(1e-3f, tq[m].y, fmaf(-c2, xc[m].y, w[4*m+1])));
                w[4*m+2] = clamp01(fmaf(1e-3f, tq[m].z, fmaf(-c2, xc[m].z, w[4*m+2])));
                w[4*m+3] = clamp01(fmaf(1e-3f, tq[m].w, fmaf(-c2, xc[m].w, w[4*m+3])));
            }
        } else {
            #pragma unroll
            for (int m = 0; m < 8; ++m) {
                w[4*m+0] = clamp01(fmaf(-c2, xc[m].x, w[4*m+0]));
                w[4*m+1] = clamp01(fmaf(-c2, xc[m].y, w[4*m+1]));
                w[4*m+2] = clamp01(fmaf(-c2, xc[m].z, w[4*m+2]));
                w[4*m+3] = clamp01(fmaf(-c2, xc[m].w, w[4*m+3]));
            }
        }

        // ---- (6) reduce LAST: consumed by step t+1's syn update ----
        syn = fmaf(0.8f, syn, wave_sum64((a0 + a1) + (a2 + a3)));
    };

    for (int t = 0; t < T_STEPS - 2; t += 2) {
        step(t,     true, xa, xb);
        step(t + 1, true, xb, xa);
    }
    step(T_STEPS - 2, true,  xa, xb);   // t=126, prefetches row 127
    step(T_STEPS - 1, false, xb, xa);   // t=127, no prefetch

}

extern "C" void kernel_launch(void* const* d_in, const int* in_sizes, int n_in,
                              void* d_out, int out_size, void* d_ws, size_t ws_size,
                              hipStream_t stream) {
    const float* x  = (const float*)d_in[0];   // exc_currents [128, 2048] f32
    const float* w0 = (const float*)d_in[1];   // w_exc [2048, 2048] f32
    // d_in[2] (w_inh) unused: inhibitory layer does not affect the output
    float* out = (float*)d_out;                // spikes [128, 2048] f32

    float* tp_ws = (float*)d_ws;               // 1 MiB, ws_size is ample
    tp_precompute_kernel<<<N_IN / 256, 256, 0, stream>>>(x, tp_ws);

    dim3 grid(N_EXC / 4);                      // 512 blocks
    dim3 block(256);                           // 4 waves = 4 neurons
    snn_exc_kernel<<<grid, block, 0, stream>>>(x, w0, tp_ws, out);
}